// Round 12
// baseline (146.520 us; speedup 1.0000x reference)
//
#include <hip/hip_runtime.h>
#include <cstdint>

#define B_    16
#define D_    64
#define N_    2304
#define DI_   128
#define S2_   0.12751875732488788f    // (1/sqrt(128)) * log2(e)  -- folded into Q
#define NB_   ((size_t)B_ * N_ * DI_)
#define KTSZ_ 4096                    // K tile: 32k x 128e shorts (swizzled image)
#define VTSZ_ 5120                    // V tile: 128d x 40k shorts (16B-aligned pitch)
#define NKT_  72                      // 32-row k tiles per batch
#define NKH_  18                      // k tiles per kh quarter
#define OF4_  1179648                 // float4s per partial (= NB_/4)

typedef __attribute__((ext_vector_type(8)))  short short8v;
typedef __attribute__((ext_vector_type(16))) float f32x16;

#if defined(__has_builtin)
#if __has_builtin(__builtin_amdgcn_exp2f)
#define EXP2(x) __builtin_amdgcn_exp2f(x)
#else
#define EXP2(x) exp2f(x)
#endif
#else
#define EXP2(x) exp2f(x)
#endif

__device__ __forceinline__ unsigned short f2bf(float f) {
    unsigned u = __builtin_bit_cast(unsigned, f);
    u = (u + 0x7FFFu + ((u >> 16) & 1u)) >> 16;
    return (unsigned short)u;
}
__device__ __forceinline__ float bf2f(unsigned short h) {
    unsigned u = ((unsigned)h) << 16;
    return __builtin_bit_cast(float, u);
}
__device__ __forceinline__ unsigned cvtpk_bf16(float lo, float hi) {
    unsigned r;
    asm volatile("v_cvt_pk_bf16_f32 %0, %1, %2" : "=v"(r) : "v"(lo), "v"(hi));
    return r;
}
__device__ __forceinline__ void plswap(unsigned &a, unsigned &b) {
    asm volatile("v_permlane32_swap_b32 %0, %1" : "+v"(a), "+v"(b));
}

// DMA: wave-uniform LDS base + lane*16B; per-lane global src.
__device__ __forceinline__ void stage_k(const unsigned short* g,
                                        unsigned short* l_, int w, int ln) {
    #pragma unroll
    for (int i = 0; i < 2; ++i)
        __builtin_amdgcn_global_load_lds(
            (const __attribute__((address_space(1))) void*)(g + i * 2048 + w * 512 + ln * 8),
            (__attribute__((address_space(3))) void*)(l_ + i * 2048 + w * 512), 16, 0, 0);
}
__device__ __forceinline__ void stage_v(const unsigned short* g,
                                        unsigned short* l_, int w, int ln, int t) {
    #pragma unroll
    for (int i = 0; i < 2; ++i)
        __builtin_amdgcn_global_load_lds(
            (const __attribute__((address_space(1))) void*)(g + i * 2048 + w * 512 + ln * 8),
            (__attribute__((address_space(3))) void*)(l_ + i * 2048 + w * 512), 16, 0, 0);
    if (t < 128)
        __builtin_amdgcn_global_load_lds(
            (const __attribute__((address_space(1))) void*)(g + 4096 + w * 512 + ln * 8),
            (__attribute__((address_space(3))) void*)(l_ + 4096 + w * 512), 16, 0, 0);
}

// ---------------------------------------------------------------------------
// Kernel 0: block0 -> W3p [384][88] bf16; blocks 1..144 -> zero Zg (36864 f32)
// ---------------------------------------------------------------------------
__global__ __launch_bounds__(256) void prep_kernel(
    const float* __restrict__ Wq, const float* __restrict__ Wk,
    const float* __restrict__ Wv, unsigned short* __restrict__ W3p,
    float* __restrict__ Zg)
{
    const int t = threadIdx.x;
    if (blockIdx.x == 0) {
        for (int r = t; r < 384; r += 256) {
            const float* src = (r < 128) ? (Wq + r * 66)
                             : (r < 256) ? (Wk + (r - 128) * 66) : (Wv + (r - 256) * 66);
            for (int c = 0; c < 66; ++c) W3p[r * 88 + c] = f2bf(src[c]);
            for (int c = 66; c < 88; ++c) W3p[r * 88 + c] = 0;
        }
    } else {
        Zg[(blockIdx.x - 1) * 256 + t] = 0.0f;
    }
}

// ---------------------------------------------------------------------------
// Kernel 1: QKV projection via MFMA.  Q scaled by S2_ at store time.
// K written directly as swizzled tile images.  grid 16b x 18nt(128), 256 thr.
// (verified r7)
// ---------------------------------------------------------------------------
__global__ __launch_bounds__(256) void qkv_kernel(
    const float* __restrict__ x, const unsigned short* __restrict__ W3p,
    unsigned short* __restrict__ Qb, unsigned short* __restrict__ Ksw,
    unsigned short* __restrict__ Vn)
{
    __shared__ unsigned short Es[128 * 88];
    const int t = threadIdx.x;
    const int b = blockIdx.x / 18, nt = blockIdx.x - b * 18;
    const int n0 = nt * 128;

    {   // x -> Es transposed bf16 (cols 0..63)
        const int d = t & 63, q4 = t >> 6;
        const float* xp = x + ((size_t)b * D_ + d) * N_ + n0 + q4 * 32;
        float xv[32];
        #pragma unroll
        for (int i = 0; i < 8; ++i) *(float4*)(xv + 4 * i) = *(const float4*)(xp + 4 * i);
        #pragma unroll
        for (int i = 0; i < 32; ++i) Es[(q4 * 32 + i) * 88 + d] = f2bf(xv[i]);
    }
    if (t < 128) {  // coords + zero pad
        int n = n0 + t;
        int ix = n / 48, iy = n - ix * 48;
        Es[t * 88 + 64] = f2bf(-1.0f + ((float)ix + 0.5f) * (2.0f / 48.0f));
        Es[t * 88 + 65] = f2bf(-1.0f + ((float)iy + 0.5f) * (2.0f / 48.0f));
        #pragma unroll
        for (int m = 0; m < 11; ++m) *(unsigned*)&Es[t * 88 + 66 + 2 * m] = 0;
    }
    __syncthreads();

    const int l = t & 63, w = t >> 6;
    const int m32 = l & 31, H = l >> 5;
    const int colbase = w * 96;
    #pragma unroll
    for (int nf = 0; nf < 4; ++nf) {
        f32x16 acc[3];
        #pragma unroll
        for (int of = 0; of < 3; ++of)
            #pragma unroll
            for (int i = 0; i < 16; ++i) acc[of][i] = 0.0f;
        #pragma unroll
        for (int kc = 0; kc < 5; ++kc) {
            short8v a = *(const short8v*)&Es[(nf * 32 + m32) * 88 + kc * 16 + H * 8];
            #pragma unroll
            for (int of = 0; of < 3; ++of) {
                short8v bf = *(const short8v*)&W3p[(colbase + of * 32 + m32) * 88 + kc * 16 + H * 8];
                acc[of] = __builtin_amdgcn_mfma_f32_32x32x16_bf16(a, bf, acc[of], 0, 0, 0);
            }
        }
        #pragma unroll
        for (int of = 0; of < 3; ++of) {
            const int col0 = colbase + of * 32;
            const int mi = col0 >> 7, e0 = col0 & 127;
            const int e = e0 + m32;
            if (mi == 0) {          // Q rows, scaled
                #pragma unroll
                for (int r = 0; r < 16; ++r) {
                    int n = n0 + nf * 32 + (r & 3) + 8 * (r >> 2) + 4 * H;
                    Qb[((size_t)b * N_ + n) * DI_ + e] = f2bf(acc[of][r] * S2_);
                }
            } else if (mi == 1) {   // K -> swizzled tile image
                const size_t tbase = ((size_t)b * NKT_ + nt * 4 + nf) * KTSZ_;
                const int cx = e >> 3, ei = e & 7;
                #pragma unroll
                for (int r = 0; r < 16; ++r) {
                    int rr = (r & 3) + 8 * (r >> 2) + 4 * H;
                    Ksw[tbase + rr * 128 + ((cx ^ (rr & 15)) * 8) + ei] = f2bf(acc[of][r]);
                }
            } else {                // V rows
                #pragma unroll
                for (int r = 0; r < 16; ++r) {
                    int n = n0 + nf * 32 + (r & 3) + 8 * (r >> 2) + 4 * H;
                    Vn[((size_t)b * N_ + n) * DI_ + e] = f2bf(acc[of][r]);
                }
            }
        }
    }
}

// ---------------------------------------------------------------------------
// Kernel 2: Zg[b][k] += sum_q exp2(dot(Q',K)).  grid 576 (16b x 9qt x 4kh),
// 256 thr; wave owns 64 q (2 frags -> 2 MFMA per LDS read).  r7 sync:
// stage at top, vmcnt(0)+__syncthreads() at bottom of each step.
// ---------------------------------------------------------------------------
__global__ __launch_bounds__(256, 3) void zsum_kernel(
    const unsigned short* __restrict__ Qb, const unsigned short* __restrict__ Ksw,
    float* __restrict__ Zg)
{
    __shared__ unsigned short Ks0[KTSZ_], Ks1[KTSZ_];
    __shared__ float Zacc[576];
    const int t = threadIdx.x;
    const int blk = blockIdx.x;
    const int b = 2 * (blk & 7) + ((blk >> 3) & 1);
    const int rest = blk >> 4;           // 0..35
    const int qt = rest % 9, kh = rest / 9;
    const int q0 = qt * 256;
    const int l = t & 63, w = t >> 6;
    const int m32 = l & 31, H = l >> 5;

    for (int i = t; i < 576; i += 256) Zacc[i] = 0.0f;

    short8v qreg[2][8];   // A-frags [32q x 16e], wave owns 64 q rows
    {
        const unsigned short* qp = Qb + ((size_t)b * N_ + q0 + w * 64 + m32) * DI_ + H * 8;
        #pragma unroll
        for (int qf = 0; qf < 2; ++qf)
            #pragma unroll
            for (int ec = 0; ec < 8; ++ec)
                qreg[qf][ec] = *(const short8v*)(qp + (size_t)qf * 32 * DI_ + ec * 16);
    }
    int ka[8];
    #pragma unroll
    for (int ec = 0; ec < 8; ++ec)
        ka[ec] = m32 * 128 + (((ec * 2 + H) ^ (m32 & 15)) * 8);

    const unsigned short* kswb = Ksw + ((size_t)b * NKT_ + kh * NKH_) * KTSZ_;
    stage_k(kswb, Ks0, w, l);
    asm volatile("s_waitcnt vmcnt(0)" ::: "memory");
    __syncthreads();

#define ZSTEP(KB, KTC)                                                         \
    {                                                                          \
        f32x16 s0, s1;                                                         \
        _Pragma("unroll") for (int i = 0; i < 16; ++i) { s0[i] = 0.f; s1[i] = 0.f; } \
        __builtin_amdgcn_s_setprio(1);                                         \
        _Pragma("unroll") for (int ec = 0; ec < 8; ++ec) {                     \
            short8v bk = *(const short8v*)&(KB)[ka[ec]];                       \
            s0 = __builtin_amdgcn_mfma_f32_32x32x16_bf16(qreg[0][ec], bk, s0, 0, 0, 0); \
            s1 = __builtin_amdgcn_mfma_f32_32x32x16_bf16(qreg[1][ec], bk, s1, 0, 0, 0); \
        }                                                                      \
        __builtin_amdgcn_s_setprio(0);                                         \
        float zl = 0.0f;                                                       \
        _Pragma("unroll") for (int r = 0; r < 16; ++r)                         \
            zl += EXP2(s0[r]) + EXP2(s1[r]);                                   \
        atomicAdd(&Zacc[(KTC) * 32 + m32], zl);                                \
        asm volatile("s_waitcnt vmcnt(0)" ::: "memory");                       \
        __syncthreads();                                                       \
    }

    for (int g = 0; g < 9; ++g) {
        const int kt = 2 * g;
        stage_k(kswb + (size_t)(kt + 1) * KTSZ_, Ks1, w, l);
        ZSTEP(Ks0, kt);
        if (kt + 2 < NKH_) stage_k(kswb + (size_t)(kt + 2) * KTSZ_, Ks0, w, l);
        ZSTEP(Ks1, kt + 1);
    }
#undef ZSTEP

    for (int i = t; i < 576; i += 256)
        atomicAdd(&Zg[(size_t)b * N_ + kh * 576 + i], Zacc[i]);
}

// ---------------------------------------------------------------------------
// Kernel 3: Vn + Zg -> Vsw tiles [128 d][pitch 40] (/Z folded).  grid 16 x 72.
// (verified r7)
// ---------------------------------------------------------------------------
__global__ __launch_bounds__(256) void repackV_kernel(
    const unsigned short* __restrict__ Vn, const float* __restrict__ Zg,
    unsigned short* __restrict__ Vsw)
{
    __shared__ unsigned short Vstg[32 * 132];
    __shared__ float zinv[32];
    const int blk = blockIdx.x;
    const int b = blk / NKT_, kt = blk - b * NKT_;
    const int t = threadIdx.x;
    const int k0 = kt * 32;
    {
        const int k = t >> 3, c = (t & 7) * 16;
        const unsigned short* src = Vn + ((size_t)b * N_ + k0 + k) * DI_ + c;
        *(int4*)&Vstg[k * 132 + c]     = *(const int4*)(src);
        *(int4*)&Vstg[k * 132 + c + 8] = *(const int4*)(src + 8);
    }
    if (t < 32) zinv[t] = 1.0f / Zg[(size_t)b * N_ + k0 + t];
    __syncthreads();
    unsigned short* dstt = Vsw + ((size_t)b * NKT_ + kt) * VTSZ_;
    const int d = t & 127, part = t >> 7;
    #pragma unroll
    for (int g = 0; g < 4; ++g) {
        unsigned short sv[4];
        #pragma unroll
        for (int j = 0; j < 4; ++j) {
            int k = part * 16 + g * 4 + j;
            sv[j] = f2bf(bf2f(Vstg[k * 132 + d]) * zinv[k]);
        }
        *(int2*)(dstt + d * 40 + part * 16 + g * 4) = *(const int2*)sv;
    }
}

// ---------------------------------------------------------------------------
// Kernel 4: partial Out^T = Vz^T . P over one kh quarter.
// grid 1152 (16b x 18qt x 4kh), 256 thr; kh0 -> out, kh1..3 -> Op[kh-1].
// r7 sync (stage top, vmcnt(0)+__syncthreads() bottom); merged sacc chain +
// fused exp2->cvt_pk for register trim (target <=170 unified regs, 3 blk/CU).
// ---------------------------------------------------------------------------
__global__ __launch_bounds__(256, 3) void attn_kernel(
    const unsigned short* __restrict__ Qb, const unsigned short* __restrict__ Ksw,
    const unsigned short* __restrict__ Vsw,
    float* __restrict__ O0, float* __restrict__ Op)
{
    __shared__ unsigned short Ks0[KTSZ_], Ks1[KTSZ_];
    __shared__ unsigned short Vs0[VTSZ_], Vs1[VTSZ_];
    const int t = threadIdx.x;
    const int blk = blockIdx.x;
    const int b = 2 * (blk & 7) + ((blk >> 3) & 1);
    const int rest = blk >> 4;
    const int qt = rest % 18, kh = rest / 18;
    const int q0 = qt * 128;
    const int l = t & 63, w = t >> 6;
    const int m32 = l & 31, H = l >> 5;

    short8v qreg[8];
    {
        const unsigned short* qp = Qb + ((size_t)b * N_ + q0 + w * 32 + m32) * DI_ + H * 8;
        #pragma unroll
        for (int ec = 0; ec < 8; ++ec) qreg[ec] = *(const short8v*)(qp + ec * 16);
    }
    f32x16 oacc[4];
    #pragma unroll
    for (int df = 0; df < 4; ++df)
        #pragma unroll
        for (int i = 0; i < 16; ++i) oacc[df][i] = 0.0f;

    int ka[8];
    #pragma unroll
    for (int ec = 0; ec < 8; ++ec)
        ka[ec] = m32 * 128 + (((ec * 2 + H) ^ (m32 & 15)) * 8);
    const int vb0 = m32 * 40 + H * 8;

    const unsigned short* kswb = Ksw + ((size_t)b * NKT_ + kh * NKH_) * KTSZ_;
    const unsigned short* vswb = Vsw + ((size_t)b * NKT_ + kh * NKH_) * VTSZ_;
    stage_k(kswb, Ks0, w, l);
    stage_v(vswb, Vs0, w, l, t);
    asm volatile("s_waitcnt vmcnt(0)" ::: "memory");
    __syncthreads();

#define PSTEP(KB, VB)                                                          \
    {                                                                          \
        f32x16 sacc;                                                           \
        _Pragma("unroll") for (int i = 0; i < 16; ++i) sacc[i] = 0.f;          \
        __builtin_amdgcn_s_setprio(1);                                         \
        _Pragma("unroll") for (int ec = 0; ec < 8; ++ec) {                     \
            short8v ak = *(const short8v*)&(KB)[ka[ec]];                       \
            sacc = __builtin_amdgcn_mfma_f32_32x32x16_bf16(ak, qreg[ec], sacc, 0, 0, 0); \
        }                                                                      \
        __builtin_amdgcn_s_setprio(0);                                         \
        unsigned c0[4], c1[4];                                                 \
        _Pragma("unroll") for (int m = 0; m < 4; ++m) {                        \
            float e0 = EXP2(sacc[4 * m]),     e1 = EXP2(sacc[4 * m + 1]);      \
            float e2 = EXP2(sacc[4 * m + 2]), e3 = EXP2(sacc[4 * m + 3]);      \
            c0[m] = cvtpk_bf16(e0, e1);                                        \
            c1[m] = cvtpk_bf16(e2, e3);                                        \
        }                                                                      \
        short8v pB[2];                                                         \
        _Pragma("unroll") for (int kq = 0; kq < 2; ++kq) {                     \
            unsigned d0 = c0[2 * kq], d2 = c0[2 * kq + 1]; plswap(d0, d2);     \
            unsigned d1 = c1[2 * kq], d3 = c1[2 * kq + 1]; plswap(d1, d3);     \
            int4 t4; t4.x = (int)d0; t4.y = (int)d1; t4.z = (int)d2; t4.w = (int)d3; \
            pB[kq] = __builtin_bit_cast(short8v, t4);                          \
        }                                                                      \
        __builtin_amdgcn_s_setprio(1);                                         \
        _Pragma("unroll") for (int df = 0; df < 4; ++df) {                     \
            _Pragma("unroll") for (int kq = 0; kq < 2; ++kq) {                 \
                short8v av = *(const short8v*)&(VB)[vb0 + df * 1280 + kq * 16]; \
                oacc[df] = __builtin_amdgcn_mfma_f32_32x32x16_bf16(av, pB[kq], oacc[df], 0, 0, 0); \
            }                                                                  \
        }                                                                      \
        __builtin_amdgcn_s_setprio(0);                                         \
        asm volatile("s_waitcnt vmcnt(0)" ::: "memory");                       \
        __syncthreads();                                                       \
    }

    for (int kt = 0; kt < NKH_; kt += 2) {
        stage_k(kswb + (size_t)(kt + 1) * KTSZ_, Ks1, w, l);
        stage_v(vswb + (size_t)(kt + 1) * VTSZ_, Vs1, w, l, t);
        PSTEP(Ks0, Vs0);
        if (kt + 2 < NKH_) {
            stage_k(kswb + (size_t)(kt + 2) * KTSZ_, Ks0, w, l);
            stage_v(vswb + (size_t)(kt + 2) * VTSZ_, Vs0, w, l, t);
        }
        PSTEP(Ks1, Vs1);
    }
#undef PSTEP

    float* outp = (kh == 0 ? O0 : (Op + (size_t)(kh - 1) * NB_))
                + ((size_t)b * N_ + q0 + w * 32 + m32) * DI_;
    #pragma unroll
    for (int df = 0; df < 4; ++df)
        #pragma unroll
        for (int r = 0; r < 16; ++r) {
            int d = df * 32 + (r & 3) + 8 * (r >> 2) + 4 * H;
            outp[d] = oacc[df][r];
        }
}

// ---------------------------------------------------------------------------
// Kernel 5: out += Op0 + Op1 + Op2.  One float4/thread, grid 4608 x 256.
// ---------------------------------------------------------------------------
__global__ __launch_bounds__(256) void reduce_kernel(
    float* __restrict__ out, const float* __restrict__ part)
{
    const size_t idx = (size_t)blockIdx.x * 256 + threadIdx.x;
    float4 p0 = ((const float4*)part)[idx];
    float4 p1 = ((const float4*)part)[idx + (size_t)OF4_];
    float4 p2 = ((const float4*)part)[idx + 2 * (size_t)OF4_];
    float4 o  = ((float4*)out)[idx];
    o.x += p0.x + p1.x + p2.x;
    o.y += p0.y + p1.y + p2.y;
    o.z += p0.z + p1.z + p2.z;
    o.w += p0.w + p1.w + p2.w;
    ((float4*)out)[idx] = o;
}

// ---------------------------------------------------------------------------
extern "C" void kernel_launch(void* const* d_in, const int* in_sizes, int n_in,
                              void* d_out, int out_size, void* d_ws, size_t ws_size,
                              hipStream_t stream)
{
    const float* x  = (const float*)d_in[0];
    const float* Wq = (const float*)d_in[1];
    const float* Wk = (const float*)d_in[2];
    const float* Wv = (const float*)d_in[3];

    // Vn aliases the head of Op: Vn dead after repackV; Op first written by
    // attn (launched later, stream-ordered).
    unsigned short* Qb  = (unsigned short*)d_ws;            // [B][N][128] (pre-scaled)
    unsigned short* Ksw = Qb  + NB_;                        // [B][72] swizzled K tiles
    unsigned short* Vsw = Ksw + NB_;                        // [B][72] V tiles pitch 40
    unsigned short* W3p = Vsw + (size_t)B_ * NKT_ * VTSZ_;  // [384][88]
    float*          Zg  = (float*)(W3p + 384 * 88);         // [B][N]
    float*          Op  = Zg + (size_t)B_ * N_;             // 3 x [B][N][128] partials
    unsigned short* Vn  = (unsigned short*)Op;              // [B][N][128] (aliased)
    float* out = (float*)d_out;

    prep_kernel   <<<145,  256, 0, stream>>>(Wq, Wk, Wv, W3p, Zg);
    qkv_kernel    <<<288,  256, 0, stream>>>(x, W3p, Qb, Ksw, Vn);
    zsum_kernel   <<<576,  256, 0, stream>>>(Qb, Ksw, Zg);
    repackV_kernel<<<1152, 256, 0, stream>>>(Vn, Zg, Vsw);
    attn_kernel   <<<1152, 256, 0, stream>>>(Qb, Ksw, Vsw, out, Op);
    reduce_kernel <<<4608, 256, 0, stream>>>(out, Op);
}